// Round 14
// baseline (15.195 us; speedup 1.0000x reference)
//
#include <hip/hip_runtime.h>
#include <hip/hip_bf16.h>

#define HH   64
#define DYF  0.0009765625f            // 1/1024
#define SCL  2.8853900817779268f      // 2*log2(e): tanh(x) = 1 - 2/(2^(SCL*x)+1)
#define CJ2  (63.0f / 1023.0f)        // fine index -> coarse position (M=64)
#define INV2 (1023.0f / 63.0f)        // coarse -> fine

typedef __attribute__((ext_vector_type(4)))  float f32x4;
typedef __attribute__((ext_vector_type(16))) float f32x16;
typedef __attribute__((ext_vector_type(8)))  short bf16x8s;

// coarse node y-value: linspace(DY, 1-DY, 64)
__device__ __forceinline__ float ynode(int m) {
  return DYF + (float)m * ((1.0f - 2.0f * DYF) / 63.0f);
}

__device__ __forceinline__ ushort bf16bits(float v) {
  __hip_bfloat16 hb = __float2bfloat16(v);
  return *reinterpret_cast<ushort*>(&hb);
}

__device__ __forceinline__ float bfval(ushort u) {
  unsigned int b = ((unsigned int)u) << 16;
  return __uint_as_float(b);
}

// ---------------- single node: 63 blocks x 256 threads (4 waves) ------------
// Block I: waves 0-1 compute U(I) (jc tiles 0,1), waves 2-3 compute U(I+1).
// Then block writes out[i] for its 16-17 owned fine i's. Plain stores only.
__global__ __launch_bounds__(256) void fused_kernel(
    const float* __restrict__ f,   const float* __restrict__ ys,
    const float* __restrict__ W1,  const float* __restrict__ b1,
    const float* __restrict__ W2,  const float* __restrict__ b2,
    const float* __restrict__ W3,  const float* __restrict__ b3,
    const float* __restrict__ Hw1, const float* __restrict__ Hb1,
    const float* __restrict__ Hw2, const float* __restrict__ Hb2,
    float* __restrict__ out)
{
  __shared__ float UPL[4];      // per-wave U partials: [0..1]=I, [2..3]=I+1
  __shared__ float homL[17];
  __shared__ float GL, SW3L;

  const int t    = threadIdx.x;
  const int wid  = t >> 6;            // wave 0..3
  const int l    = t & 63;
  const int half = l >> 5;
  const int c    = l & 31;
  const int I    = blockIdx.x;        // 0..62
  const int Iw   = I + (wid >> 1);    // this wave's coarse row (I or I+1)
  const int jt   = wid & 1;           // jc tile 0..1
  const int jc   = jt * 32 + c;       // this lane's coarse j (A-frag row)

  // owned fine-i range for interval [I, I+1]
  const int i_lo = (I * 1023 + 62) / 63;
  const int i_hi = (I == 62) ? 1023 : ((I + 1) * 1023 + 62) / 63 - 1;
  const int n_i  = i_hi - i_lo + 1;   // 16 or 17

  // ---- B fragments + column-sum --------------------------------------------
  bf16x8s B0[4], B1[4];
  float csp0 = 0.0f, csp1 = 0.0f;
  #pragma unroll
  for (int ks = 0; ks < 4; ++ks) {
    #pragma unroll
    for (int e = 0; e < 8; ++e) {
      int k = ks * 16 + half * 8 + e;
      ushort u0 = bf16bits(-2.0f * SCL * W2[k * HH + c]);
      ushort u1 = bf16bits(-2.0f * SCL * W2[k * HH + 32 + c]);
      B0[ks][e] = (short)u0;  csp0 += bfval(u0);
      B1[ks][e] = (short)u1;  csp1 += bfval(u1);
    }
  }
  csp0 += __shfl_xor(csp0, 32);
  csp1 += __shfl_xor(csp1, 32);
  const float cst0 = fmaf(-0.5f, csp0, SCL * b2[c]);
  const float cst1 = fmaf(-0.5f, csp1, SCL * b2[32 + c]);

  // ---- A-frag ingredients: Cf (lane's jc row) x AfI (wave's coarse row) ----
  const float yj = ynode(jc);
  const float yI = ynode(Iw);
  f32x4 AfI[8], Cf[8];
  #pragma unroll
  for (int ks = 0; ks < 4; ++ks) {
    #pragma unroll
    for (int q = 0; q < 2; ++q) {
      #pragma unroll
      for (int e = 0; e < 4; ++e) {
        int m = ks * 16 + half * 8 + q * 4 + e;
        AfI[ks * 2 + q][e] = __builtin_amdgcn_exp2f(SCL * yI * W1[m]);
        Cf[ks * 2 + q][e]  = __builtin_amdgcn_exp2f(SCL * fmaf(yj, W1[HH + m], b1[m]));
      }
    }
  }

  // ---- ghat(jc): hat-weighted gather over ~33 fine j's ---------------------
  float gval = 0.0f;
  {
    int jlo = (int)ceilf((float)(jc - 1) * INV2);
    if (jlo < 0) jlo = 0;
    #pragma unroll 1
    for (int s = 0; s < 34; ++s) {
      int j = jlo + s;
      if (j > 1023) break;
      float w = 1.0f - fabsf((float)j * CJ2 - (float)jc);
      if (w > 0.0f) gval = fmaf(w, f[j], gval);
    }
  }
  const float w3d0 = -2.0f * DYF * W3[c];
  const float w3d1 = -2.0f * DYF * W3[32 + c];

  // ---- layer-1 r -> bf16 -> MFMA (rows = jc, cols = l) ---------------------
  f32x16 acc0, acc1;
  #pragma unroll
  for (int r = 0; r < 16; ++r) { acc0[r] = cst0; acc1[r] = cst1; }

  #pragma unroll
  for (int ks = 0; ks < 4; ++ks) {
    float tt[8];
    f32x4 z0 = AfI[ks * 2]     * Cf[ks * 2];      // exp2(a'_I + c'_jc)
    f32x4 z1 = AfI[ks * 2 + 1] * Cf[ks * 2 + 1];
    #pragma unroll
    for (int e = 0; e < 4; ++e) {
      tt[e]     = __builtin_amdgcn_rcpf(z0[e] + 1.0f);
      tt[4 + e] = __builtin_amdgcn_rcpf(z1[e] + 1.0f);
    }
    union { bf16x8s s; __hip_bfloat162 h[4]; } fr;
    fr.h[0] = __float22bfloat162_rn(make_float2(tt[0], tt[1]));
    fr.h[1] = __float22bfloat162_rn(make_float2(tt[2], tt[3]));
    fr.h[2] = __float22bfloat162_rn(make_float2(tt[4], tt[5]));
    fr.h[3] = __float22bfloat162_rn(make_float2(tt[6], tt[7]));
    acc0 = __builtin_amdgcn_mfma_f32_32x32x16_bf16(fr.s, B0[ks], acc0, 0, 0, 0);
    acc1 = __builtin_amdgcn_mfma_f32_32x32x16_bf16(fr.s, B1[ks], acc1, 0, 0, 0);
  }

  // ---- epilogue: tanh, weight by ghat[row]*W3[col], full 64-lane reduce ----
  float s0 = 0.0f, s1 = 0.0f;
  #pragma unroll
  for (int r = 0; r < 16; ++r) {
    int row = (r & 3) + 8 * (r >> 2) + 4 * half;
    float g_r = __shfl(gval, row);               // lane `row` holds ghat(jt*32+row)
    float e0 = __builtin_amdgcn_exp2f(acc0[r]);
    float r0 = __builtin_amdgcn_rcpf(e0 + 1.0f);
    float e1 = __builtin_amdgcn_exp2f(acc1[r]);
    float r1 = __builtin_amdgcn_rcpf(e1 + 1.0f);
    s0 = fmaf(r0, g_r, s0);
    s1 = fmaf(r1, g_r, s1);
  }
  float v = fmaf(s0, w3d0, s1 * w3d1);
  v += __shfl_xor(v, 1);
  v += __shfl_xor(v, 2);
  v += __shfl_xor(v, 4);
  v += __shfl_xor(v, 8);
  v += __shfl_xor(v, 16);
  v += __shfl_xor(v, 32);
  if (l == 0) UPL[wid] = v;

  // ---- hom for owned fine i's (wid-strided loop; lane = channel) -----------
  #pragma unroll 1
  for (int it = wid; it < n_i; it += 4) {
    float yi = ys[i_lo + it];
    float e = __builtin_amdgcn_exp2f(SCL * fmaf(yi, Hw1[l], Hb1[l]));
    float th = 1.0f - 2.0f * __builtin_amdgcn_rcpf(e + 1.0f);   // tanh
    float h = Hw2[l] * th;
    h += __shfl_xor(h, 1);  h += __shfl_xor(h, 2);  h += __shfl_xor(h, 4);
    h += __shfl_xor(h, 8);  h += __shfl_xor(h, 16); h += __shfl_xor(h, 32);
    if (l == 0) homL[it] = h;
  }

  // ---- G = sum f, sw3 = sum W3 (wave 1) ------------------------------------
  if (wid == 1) {
    const float4* f4 = (const float4*)f;
    float G = 0.0f;
    #pragma unroll
    for (int q = 0; q < 4; ++q) {
      float4 fv = f4[l * 4 + q];
      G += fv.x + fv.y + fv.z + fv.w;
    }
    G += __shfl_xor(G, 1);  G += __shfl_xor(G, 2);  G += __shfl_xor(G, 4);
    G += __shfl_xor(G, 8);  G += __shfl_xor(G, 16); G += __shfl_xor(G, 32);
    float sw3 = W3[l];
    sw3 += __shfl_xor(sw3, 1);  sw3 += __shfl_xor(sw3, 2);  sw3 += __shfl_xor(sw3, 4);
    sw3 += __shfl_xor(sw3, 8);  sw3 += __shfl_xor(sw3, 16); sw3 += __shfl_xor(sw3, 32);
    if (l == 0) { GL = G; SW3L = sw3; }
  }

  __syncthreads();

  // ---- final: out[i] = lerp(U(I),U(I+1)) + hom + const, plain store --------
  if (t < n_i) {
    int i = i_lo + t;
    float U0 = UPL[0] + UPL[1];
    float U1 = UPL[2] + UPL[3];
    float tt = (float)i * CJ2 - (float)I;
    out[i] = fmaf(tt, U1 - U0, U0) + homL[t] + Hb2[0]
             + (b3[0] + SW3L) * GL * DYF;
  }
}

extern "C" void kernel_launch(void* const* d_in, const int* in_sizes, int n_in,
                              void* d_out, int out_size, void* d_ws, size_t ws_size,
                              hipStream_t stream) {
  const float* f   = (const float*)d_in[0];
  const float* ys  = (const float*)d_in[1];
  const float* W1  = (const float*)d_in[2];
  const float* b1  = (const float*)d_in[3];
  const float* W2  = (const float*)d_in[4];
  const float* b2  = (const float*)d_in[5];
  const float* W3  = (const float*)d_in[6];
  const float* b3  = (const float*)d_in[7];
  const float* Hw1 = (const float*)d_in[8];
  const float* Hb1 = (const float*)d_in[9];
  const float* Hw2 = (const float*)d_in[10];
  const float* Hb2 = (const float*)d_in[11];
  float* out = (float*)d_out;

  fused_kernel<<<63, 256, 0, stream>>>(f, ys, W1, b1, W2, b2, W3, b3,
                                       Hw1, Hb1, Hw2, Hb2, out);
}